// Round 10
// baseline (81.907 us; speedup 1.0000x reference)
//
#include <hip/hip_runtime.h>

#define B_SZ   1024
#define OUT_SZ 512
#define IN_SZ  1024
#define NST    64                 // K' = 2048 -> 64 MFMA k-steps of 32
#define KSPLIT 4
#define KPB    (NST / KSPLIT)     // 16 steps per gemm block
#define CST    4                  // steps per staged chunk
#define NCH    (KPB / CST)        // 4 chunks

typedef __bf16 bf16x8 __attribute__((ext_vector_type(8)));
typedef float  f32x4  __attribute__((ext_vector_type(4)));

// ws layout (bytes): Apan 4 MB | Bpan 2 MB | r 2 KB (+pad) | part 8 MB
#define APAN_ELEM ((size_t)64 * NST * 64 * 8)
#define BPAN_ELEM ((size_t)32 * NST * 64 * 8)
#define OFF_BP   (APAN_ELEM * 2)
#define OFF_R    (OFF_BP + BPAN_ELEM * 2)
#define OFF_PART (OFF_R + 8192)

#define NBLK_A 1024
#define NBLK_B 512
#define NBLK_R 128

// Convert ONCE into fragment-native bf16 panels:
//   Apan[mt][st][lane][8] = A[b=mt*16+(lane&15)][k=st*32+(lane>>4)*8+j]
//   A = x^2 (k<1024) | x ; B = u^2 | -2u^2w ; r[o] = sum (uw)^2 in fp32.
__global__ __launch_bounds__(256) void rbf_prep(
    const float* __restrict__ x, const float* __restrict__ w,
    const float* __restrict__ u, __bf16* __restrict__ Apan,
    __bf16* __restrict__ Bpan, float* __restrict__ rbuf)
{
    const int blk = blockIdx.x;
    if (blk < NBLK_A) {
        int gid  = blk * 256 + threadIdx.x;
        int lane = gid & 63, unit = gid >> 6;
        int kStep = unit & 63;
        int b     = (unit >> 6) * 16 + (lane & 15);
        int kk    = kStep * 32 + (lane >> 4) * 8;
        bf16x8 v;
        if (kk < IN_SZ) {
            const float4 f0 = *(const float4*)&x[(size_t)b * IN_SZ + kk];
            const float4 f1 = *(const float4*)&x[(size_t)b * IN_SZ + kk + 4];
            float f[8] = {f0.x, f0.y, f0.z, f0.w, f1.x, f1.y, f1.z, f1.w};
            #pragma unroll
            for (int j = 0; j < 8; ++j) v[j] = (__bf16)(f[j] * f[j]);
        } else {
            int i0 = kk - IN_SZ;
            const float4 f0 = *(const float4*)&x[(size_t)b * IN_SZ + i0];
            const float4 f1 = *(const float4*)&x[(size_t)b * IN_SZ + i0 + 4];
            float f[8] = {f0.x, f0.y, f0.z, f0.w, f1.x, f1.y, f1.z, f1.w};
            #pragma unroll
            for (int j = 0; j < 8; ++j) v[j] = (__bf16)f[j];
        }
        *(bf16x8*)&Apan[(size_t)gid * 8] = v;
    } else if (blk < NBLK_A + NBLK_B) {
        int gid  = (blk - NBLK_A) * 256 + threadIdx.x;
        int lane = gid & 63, unit = gid >> 6;
        int kStep = unit & 63;
        int o     = (unit >> 6) * 16 + (lane & 15);
        int kk    = kStep * 32 + (lane >> 4) * 8;
        bf16x8 v;
        if (kk < IN_SZ) {
            const float4 u0 = *(const float4*)&u[(size_t)o * IN_SZ + kk];
            const float4 u1 = *(const float4*)&u[(size_t)o * IN_SZ + kk + 4];
            float uf[8] = {u0.x, u0.y, u0.z, u0.w, u1.x, u1.y, u1.z, u1.w};
            #pragma unroll
            for (int j = 0; j < 8; ++j) v[j] = (__bf16)(uf[j] * uf[j]);
        } else {
            int i0 = kk - IN_SZ;
            const float4 u0 = *(const float4*)&u[(size_t)o * IN_SZ + i0];
            const float4 u1 = *(const float4*)&u[(size_t)o * IN_SZ + i0 + 4];
            const float4 w0 = *(const float4*)&w[(size_t)o * IN_SZ + i0];
            const float4 w1 = *(const float4*)&w[(size_t)o * IN_SZ + i0 + 4];
            float uf[8] = {u0.x, u0.y, u0.z, u0.w, u1.x, u1.y, u1.z, u1.w};
            float wf[8] = {w0.x, w0.y, w0.z, w0.w, w1.x, w1.y, w1.z, w1.w};
            #pragma unroll
            for (int j = 0; j < 8; ++j) v[j] = (__bf16)(-2.f * uf[j] * uf[j] * wf[j]);
        }
        *(bf16x8*)&Bpan[(size_t)gid * 8] = v;
    } else {
        int wv   = threadIdx.x >> 6;
        int lane = threadIdx.x & 63;
        int o    = (blk - NBLK_A - NBLK_B) * 4 + wv;
        float s = 0.f;
        #pragma unroll
        for (int c = 0; c < 4; ++c) {
            int i = lane * 16 + c * 4;
            const float4 uv = *(const float4*)&u[(size_t)o * IN_SZ + i];
            const float4 wv4 = *(const float4*)&w[(size_t)o * IN_SZ + i];
            float t0 = uv.x * wv4.x, t1 = uv.y * wv4.y, t2 = uv.z * wv4.z, t3 = uv.w * wv4.w;
            s += t0 * t0 + t1 * t1 + t2 * t2 + t3 * t3;
        }
        #pragma unroll
        for (int d = 32; d > 0; d >>= 1) s += __shfl_down(s, d);
        if (lane == 0) rbuf[o] = s;
    }
}

// async 16B global -> LDS (wave-uniform LDS base + lane*16; gptr per-lane)
__device__ __forceinline__ void ld16_lds(const __bf16* g, __bf16* l) {
    __builtin_amdgcn_global_load_lds(
        (const __attribute__((address_space(1))) void*)g,
        (__attribute__((address_space(3))) void*)l, 16, 0, 0);
}

// Pure GEMM from prepped panels. 64x64 tile, 4 waves (2x2 frags of 16x16x32),
// split-K=4 -> 512 blocks (2/CU), double-buffered global_load_lds staging.
__global__ __launch_bounds__(256) void rbf_gemm(
    const __bf16* __restrict__ Apan, const __bf16* __restrict__ Bpan,
    float* __restrict__ part)
{
    __shared__ __bf16 As[2][16 * 512];   // [buf][(mt_l*4+st)*512 + lane*8], 16 KB
    __shared__ __bf16 Bs[2][16 * 512];

    const int bid  = blockIdx.x;
    const int yt   = bid & 7;            // XCD-pinned o-slice
    const int xt   = (bid >> 3) & 15;
    const int kz   = bid >> 7;
    const int lane = threadIdx.x & 63;
    const int wv   = threadIdx.x >> 6;
    const int wm   = wv >> 1, wn = wv & 1;
    const int sBase = kz * KPB;

    // 32 stage-ops/chunk (16 A + 16 B), 8 per wave
    auto stage = [&](int c, int buf) {
        const int s0 = sBase + c * CST;
        #pragma unroll
        for (int i = 0; i < 8; ++i) {
            int f = wv * 8 + i;
            if (f < 16) {
                int mt = f >> 2, st = f & 3;
                ld16_lds(&Apan[(((size_t)(xt * 4 + mt) * NST + s0 + st) * 64 + lane) * 8],
                         &As[buf][(mt * 4 + st) * 512]);
            } else {
                int f2 = f - 16;
                int nt = f2 >> 2, st = f2 & 3;
                ld16_lds(&Bpan[(((size_t)(yt * 4 + nt) * NST + s0 + st) * 64 + lane) * 8],
                         &Bs[buf][(nt * 4 + st) * 512]);
            }
        }
    };

    f32x4 acc[2][2] = {};

    stage(0, 0);
    __syncthreads();                      // vmcnt(0) drain -> buf0 ready

    for (int c = 0; c < NCH; ++c) {
        const int buf = c & 1;
        if (c + 1 < NCH) stage(c + 1, buf ^ 1);   // in flight across compute
        #pragma unroll
        for (int st = 0; st < CST; ++st) {
            bf16x8 a0 = *(const bf16x8*)&As[buf][((wm * 2 + 0) * 4 + st) * 512 + lane * 8];
            bf16x8 a1 = *(const bf16x8*)&As[buf][((wm * 2 + 1) * 4 + st) * 512 + lane * 8];
            bf16x8 b0 = *(const bf16x8*)&Bs[buf][((wn * 2 + 0) * 4 + st) * 512 + lane * 8];
            bf16x8 b1 = *(const bf16x8*)&Bs[buf][((wn * 2 + 1) * 4 + st) * 512 + lane * 8];
            acc[0][0] = __builtin_amdgcn_mfma_f32_16x16x32_bf16(a0, b0, acc[0][0], 0, 0, 0);
            acc[0][1] = __builtin_amdgcn_mfma_f32_16x16x32_bf16(a0, b1, acc[0][1], 0, 0, 0);
            acc[1][0] = __builtin_amdgcn_mfma_f32_16x16x32_bf16(a1, b0, acc[1][0], 0, 0, 0);
            acc[1][1] = __builtin_amdgcn_mfma_f32_16x16x32_bf16(a1, b1, acc[1][1], 0, 0, 0);
        }
        __syncthreads();                  // drains next chunk's loads too
    }

    // C/D: col = lane&15 (o), row = quad*4 + reg (b)   [m89-verified]
    const int quad = lane >> 4, col = lane & 15;
    #pragma unroll
    for (int mi = 0; mi < 2; ++mi) {
        int b = xt * 64 + (wm * 2 + mi) * 16 + quad * 4;
        #pragma unroll
        for (int ni = 0; ni < 2; ++ni) {
            int o = yt * 64 + (wn * 2 + ni) * 16 + col;
            #pragma unroll
            for (int r = 0; r < 4; ++r)
                part[((size_t)kz * B_SZ + (b + r)) * OUT_SZ + o] = acc[mi][ni][r];
        }
    }
}

// z = sum_kz part + r[o]; out = a + exp(-z)*(1-2a)
__global__ __launch_bounds__(256) void rbf_reduce(
    const float* __restrict__ part, const float* __restrict__ rbuf,
    const float* __restrict__ andor, float* __restrict__ out)
{
    const int base = (blockIdx.x * 256 + threadIdx.x) * 4;
    if (base < B_SZ * OUT_SZ) {
        const int ob = base & (OUT_SZ - 1);
        float4 z = *(const float4*)&rbuf[ob];
        #pragma unroll
        for (int kz = 0; kz < KSPLIT; ++kz) {
            const float4 p = *(const float4*)&part[(size_t)kz * (B_SZ * OUT_SZ) + base];
            z.x += p.x; z.y += p.y; z.z += p.z; z.w += p.w;
        }
        const float4 a = *(const float4*)&andor[ob];
        float4 o;
        o.x = fmaf(__expf(-z.x), 1.f - 2.f * a.x, a.x);
        o.y = fmaf(__expf(-z.y), 1.f - 2.f * a.y, a.y);
        o.z = fmaf(__expf(-z.z), 1.f - 2.f * a.z, a.z);
        o.w = fmaf(__expf(-z.w), 1.f - 2.f * a.w, a.w);
        *(float4*)&out[base] = o;
    }
}

extern "C" void kernel_launch(void* const* d_in, const int* in_sizes, int n_in,
                              void* d_out, int out_size, void* d_ws, size_t ws_size,
                              hipStream_t stream) {
    const float* x = (const float*)d_in[0];   // [B, IN]
    const float* w = (const float*)d_in[1];   // [OUT, IN]
    const float* u = (const float*)d_in[2];   // [OUT, IN]
    const float* a = (const float*)d_in[3];   // [1, OUT]
    float* out = (float*)d_out;               // [B, OUT]

    char* ws = (char*)d_ws;
    __bf16* Apan = (__bf16*)ws;
    __bf16* Bpan = (__bf16*)(ws + OFF_BP);
    float*  rbuf = (float*)(ws + OFF_R);
    float*  part = (float*)(ws + OFF_PART);

    rbf_prep<<<dim3(NBLK_A + NBLK_B + NBLK_R), dim3(256), 0, stream>>>(x, w, u, Apan, Bpan, rbuf);
    rbf_gemm<<<dim3(16 * 8 * KSPLIT), dim3(256), 0, stream>>>(Apan, Bpan, part);
    rbf_reduce<<<dim3(B_SZ * OUT_SZ / 4 / 256), dim3(256), 0, stream>>>(part, rbuf, a, out);
}